// Round 11
// baseline (309.684 us; speedup 1.0000x reference)
//
#include <hip/hip_runtime.h>
#include <hip/hip_bf16.h>

// GIN layer: out = relu(((1+eps)*x + segment_sum(x[src], dst)) @ W1 + b1) @ W2 + b2
// N=50000 nodes, E=1.6M edges, D=128.

#define N_NODES 50000
#define N_EDGES 1600000
#define D 128

#define NB_H 256                 // private histograms (one owner block each)
#define CHUNK (N_EDGES / NB_H)   // 6250 edges per chunk; rank max 6249 < 65536
#define HROW 50016               // ushorts per hist row (100,032 B, 128-aligned)

#define NSLAB 4                  // gather column slabs: 32 cols = 64 B per node
#define SLAB_U2 (N_NODES * 8)    // uint2 per slab (8 uint2 = 64 B per node)
#define SLAB_U4 (N_NODES * 4)    // uint4 per slab

typedef __attribute__((ext_vector_type(8))) short short8;
typedef __attribute__((ext_vector_type(4))) float float4v;

__device__ inline unsigned short f2b(float f) {
    unsigned u = __builtin_bit_cast(unsigned, f);
    u = u + 0x7fffu + ((u >> 16) & 1u);  // RNE
    return (unsigned short)(u >> 16);
}
__device__ inline float b2f_lo(unsigned u) { return __builtin_bit_cast(float, u << 16); }
__device__ inline float b2f_hi(unsigned u) { return __builtin_bit_cast(float, u & 0xffff0000u); }

// ---------------- x f32 -> bf16 slabs (+ edge-dtype detect in block 0) ----------------
// Slab p holds cols [32p, 32p+32) of all nodes: 64 B per node, contiguous 3.2 MB.
__global__ __launch_bounds__(256) void k_cvt(const float* __restrict__ x,
                                             unsigned* __restrict__ xb2,  // uint2-granular
                                             const int* __restrict__ ei,
                                             int* __restrict__ flag) {
    if (blockIdx.x == 0) {
        __shared__ int nz;
        if (threadIdx.x == 0) nz = 0;
        __syncthreads();
        if (ei[threadIdx.x * 2 + 1] != 0) atomicAdd(&nz, 1);
        __syncthreads();
        if (threadIdx.x == 0) *flag = (nz == 0) ? 1 : 0;  // 1 => int64 layout
    }
    int i = blockIdx.x * blockDim.x + threadIdx.x;  // one float4 (4 cols) per thread
    if (i >= N_NODES * 32) return;
    int n = i >> 5;
    int c4 = i & 31;          // float4 group; cols 4*c4..4*c4+3
    int p = c4 >> 3;          // slab
    int w = c4 & 7;           // uint2 within node's 64-B slice
    float4 v = ((const float4*)x)[i];
    size_t o2 = ((size_t)p * SLAB_U2 + n * 8 + w) * 2;
    xb2[o2]     = (unsigned)f2b(v.x) | ((unsigned)f2b(v.y) << 16);
    xb2[o2 + 1] = (unsigned)f2b(v.z) | ((unsigned)f2b(v.w) << 16);
}

// ---------------- LDS histogram (packed u16 pairs) + per-edge rank ----------------
__global__ __launch_bounds__(1024) void k_hist_rank(const int* __restrict__ ei,
                                                    const int* __restrict__ flag,
                                                    unsigned* __restrict__ cntw,
                                                    int* __restrict__ rank) {
    __shared__ unsigned hist[HROW / 2];  // 25008 u32 = 100,032 B
    int b = blockIdx.x;
    for (int i = threadIdx.x; i < HROW / 2; i += 1024) hist[i] = 0u;
    __syncthreads();
    int wide = *flag;
    int e0 = b * CHUNK;
    for (int i = threadIdx.x; i < CHUNK; i += 1024) {
        int e = e0 + i;
        long long di = (long long)N_EDGES + e;
        int d = wide ? ei[di * 2] : ei[di];
        int r = 0;
        if ((unsigned)d < (unsigned)N_NODES) {
            int sh = (d & 1) * 16;
            unsigned old = atomicAdd(&hist[d >> 1], 1u << sh);
            r = (old >> sh) & 0xffffu;
        }
        rank[e] = r;  // coalesced
    }
    __syncthreads();
    unsigned* row = cntw + (size_t)b * (HROW / 2);
    for (int i = threadIdx.x; i < HROW / 2; i += 1024) row[i] = hist[i];
}

// ---------------- fused column scan + per-block scan of deg ----------------
__global__ __launch_bounds__(512) void k_colscan_scan1(unsigned short* __restrict__ cnt16,
                                                       int* __restrict__ deg,
                                                       int* __restrict__ offsets,
                                                       int* __restrict__ bsum) {
    __shared__ int tmp[512];
    int t = threadIdx.x;
    int d = blockIdx.x * 512 + t;
    int run = 0;
    if (d < N_NODES) {
        #pragma unroll 8
        for (int b = 0; b < NB_H; ++b) {
            size_t idx = (size_t)b * HROW + d;
            int v = cnt16[idx];
            cnt16[idx] = (unsigned short)run;
            run += v;
        }
        deg[d] = run;
    }
    tmp[t] = run;
    __syncthreads();
    for (int off = 1; off < 512; off <<= 1) {
        int u = (t >= off) ? tmp[t - off] : 0;
        __syncthreads();
        tmp[t] += u;
        __syncthreads();
    }
    if (d < N_NODES) offsets[d] = tmp[t] - run;
    if (t == 511) bsum[blockIdx.x] = tmp[511];
}

// ---------------- fused scan of block sums + add base ----------------
__global__ __launch_bounds__(512) void k_scan23(int* __restrict__ offsets,
                                                const int* __restrict__ bsum, int nb) {
    __shared__ int tmp[128];
    int t = threadIdx.x;
    if (t < 128) tmp[t] = (t < nb) ? bsum[t] : 0;
    __syncthreads();
    for (int off = 1; off < 128; off <<= 1) {
        int v = (t >= off && t < 128) ? tmp[t - off] : 0;
        __syncthreads();
        if (t < 128) tmp[t] += v;
        __syncthreads();
    }
    int base = (blockIdx.x == 0) ? 0 : tmp[blockIdx.x - 1];
    int gid = blockIdx.x * 512 + t;
    if (gid < N_NODES) offsets[gid] += base;
}

// ---------------- CSR place (no atomics, one edge per thread) ----------------
__global__ __launch_bounds__(1024) void k_place(const int* __restrict__ ei,
                                                const int* __restrict__ flag,
                                                const int* __restrict__ offsets,
                                                const unsigned short* __restrict__ cnt16,
                                                const int* __restrict__ rank,
                                                int* __restrict__ srcs) {
    int e = blockIdx.x * 1024 + threadIdx.x;
    if (e >= N_EDGES) return;
    int wide = *flag;
    int s = wide ? ei[(long long)e * 2] : ei[e];
    long long di = (long long)N_EDGES + e;
    int d = wide ? ei[di * 2] : ei[di];
    if ((unsigned)d < (unsigned)N_NODES && (unsigned)s < (unsigned)N_NODES) {
        int b = e / CHUNK;
        srcs[offsets[d] + cnt16[(size_t)b * HROW + d] + rank[e]] = s;
    }
}

// ---------------- gather, one column slab per launch ----------------
// Pass p touches only slab p (3.2 MB -> L2-resident per XCD). One wave per node;
// 8 neighbor groups x 8 lanes (uint2 = 4 cols each, 64 B per row-slice).
__global__ __launch_bounds__(256) void k_gather(const unsigned* __restrict__ xb2,
                                                const int* __restrict__ srcs,
                                                const int* __restrict__ offsets,
                                                const int* __restrict__ deg,
                                                unsigned* __restrict__ aggb2,  // slabbed
                                                int p) {
    int node = blockIdx.x * 4 + (threadIdx.x >> 6);
    int lane = threadIdx.x & 63;
    int g = lane >> 3;    // neighbor group 0..7
    int u = lane & 7;     // uint2 within 64-B row-slice
    int beg = offsets[node];
    int end = beg + deg[node];
    const uint2* xr = (const uint2*)(xb2 + (size_t)p * SLAB_U2 * 2);
    float a0 = 0.f, a1 = 0.f, a2 = 0.f, a3 = 0.f;
    int j = beg + g;
    for (; j + 8 < end; j += 16) {
        int s0 = __builtin_nontemporal_load(&srcs[j]);
        int s1 = __builtin_nontemporal_load(&srcs[j + 8]);
        uint2 A = xr[s0 * 8 + u];
        uint2 B = xr[s1 * 8 + u];
        a0 += b2f_lo(A.x); a1 += b2f_hi(A.x); a2 += b2f_lo(A.y); a3 += b2f_hi(A.y);
        a0 += b2f_lo(B.x); a1 += b2f_hi(B.x); a2 += b2f_lo(B.y); a3 += b2f_hi(B.y);
    }
    if (j < end) {
        int s0 = __builtin_nontemporal_load(&srcs[j]);
        uint2 A = xr[s0 * 8 + u];
        a0 += b2f_lo(A.x); a1 += b2f_hi(A.x); a2 += b2f_lo(A.y); a3 += b2f_hi(A.y);
    }
    // reduce across the 8 neighbor groups (lane bits 3..5)
    #pragma unroll
    for (int m = 8; m <= 32; m <<= 1) {
        a0 += __shfl_xor(a0, m, 64); a1 += __shfl_xor(a1, m, 64);
        a2 += __shfl_xor(a2, m, 64); a3 += __shfl_xor(a3, m, 64);
    }
    if (g == 0) {
        uint2 xs = xr[node * 8 + u];  // self term from the slab (bf16)
        float f0 = fmaf(1.001f, b2f_lo(xs.x), a0);
        float f1 = fmaf(1.001f, b2f_hi(xs.x), a1);
        float f2 = fmaf(1.001f, b2f_lo(xs.y), a2);
        float f3 = fmaf(1.001f, b2f_hi(xs.y), a3);
        size_t o2 = ((size_t)p * SLAB_U2 + node * 8 + u) * 2;
        __builtin_nontemporal_store((unsigned)f2b(f0) | ((unsigned)f2b(f1) << 16), &aggb2[o2]);
        __builtin_nontemporal_store((unsigned)f2b(f2) | ((unsigned)f2b(f3) << 16), &aggb2[o2 + 1]);
    }
}

// ---------------- fused MLP: out = relu(A@W1+b1)@W2 + b2 ----------------
// Each wave's K-loops read only its own 32 A-rows, so h overwrites those rows
// in LDS with no inter-wave hazard (single barrier after staging).
#define LPAD 136
__global__ __launch_bounds__(256, 1) void k_mlp(const unsigned* __restrict__ aggb2,
                                                const float* __restrict__ W1g,
                                                const float* __restrict__ b1g,
                                                const float* __restrict__ W2g,
                                                const float* __restrict__ b2g,
                                                float* __restrict__ out, int M) {
    __shared__ short Al[128 * LPAD];    // [row][k] bf16
    __shared__ short W1t[128 * LPAD];   // [n][k]
    __shared__ short W2t[128 * LPAD];   // [n][k]
    __shared__ float bl1[128], bl2[128];

    int t = threadIdx.x;
    int row0 = blockIdx.x * 128;

    // stage A from slabbed aggb (uint4 = 8 cols; slab s = c>>2, q = c&3)
    const uint4* A16 = (const uint4*)aggb2;
    #pragma unroll
    for (int i = 0; i < 8; ++i) {
        int idx = i * 256 + t;      // 0..2047
        int r = idx >> 4;           // 0..127
        int c = idx & 15;           // logical uint4 within row
        int s = c >> 2, q = c & 3;
        uint4 v = make_uint4(0u, 0u, 0u, 0u);
        int grow = row0 + r;
        if (grow < M) v = A16[(size_t)s * SLAB_U4 + grow * 4 + q];
        *(uint4*)&Al[r * LPAD + c * 8] = v;
    }
    // stage W1^T and W2^T (f32 -> bf16)
    const float4* W14 = (const float4*)W1g;
    const float4* W24 = (const float4*)W2g;
    #pragma unroll
    for (int i = 0; i < 16; ++i) {
        int idx = i * 256 + t;
        int k = idx >> 5;
        int n4 = idx & 31;
        float4 v1 = W14[k * 32 + n4];
        float4 v2 = W24[k * 32 + n4];
        W1t[(n4 * 4 + 0) * LPAD + k] = (short)f2b(v1.x);
        W1t[(n4 * 4 + 1) * LPAD + k] = (short)f2b(v1.y);
        W1t[(n4 * 4 + 2) * LPAD + k] = (short)f2b(v1.z);
        W1t[(n4 * 4 + 3) * LPAD + k] = (short)f2b(v1.w);
        W2t[(n4 * 4 + 0) * LPAD + k] = (short)f2b(v2.x);
        W2t[(n4 * 4 + 1) * LPAD + k] = (short)f2b(v2.y);
        W2t[(n4 * 4 + 2) * LPAD + k] = (short)f2b(v2.z);
        W2t[(n4 * 4 + 3) * LPAD + k] = (short)f2b(v2.w);
    }
    if (t < 32) ((float4*)bl1)[t] = ((const float4*)b1g)[t];
    else if (t < 64) ((float4*)bl2)[t - 32] = ((const float4*)b2g)[t - 32];
    __syncthreads();

    int wave = t >> 6;
    int lane = t & 63;
    int quad = lane >> 4;
    int l16 = lane & 15;
    int rowbase = wave * 32;

    float4v acc[2][8];
    #pragma unroll
    for (int mt = 0; mt < 2; ++mt)
        #pragma unroll
        for (int nt = 0; nt < 8; ++nt)
            acc[mt][nt] = (float4v){0.f, 0.f, 0.f, 0.f};

    // ---- layer 1 ----
    #pragma unroll
    for (int kc = 0; kc < 4; ++kc) {
        int koff = kc * 32 + quad * 8;
        short8 a0 = *(const short8*)&Al[(rowbase + l16) * LPAD + koff];
        short8 a1 = *(const short8*)&Al[(rowbase + 16 + l16) * LPAD + koff];
        #pragma unroll
        for (int nt = 0; nt < 8; ++nt) {
            short8 bfr = *(const short8*)&W1t[(nt * 16 + l16) * LPAD + koff];
            acc[0][nt] = __builtin_amdgcn_mfma_f32_16x16x32_bf16(a0, bfr, acc[0][nt], 0, 0, 0);
            acc[1][nt] = __builtin_amdgcn_mfma_f32_16x16x32_bf16(a1, bfr, acc[1][nt], 0, 0, 0);
        }
    }
    // h = relu(acc + b1) -> back into this wave's own Al rows (bf16)
    #pragma unroll
    for (int mt = 0; mt < 2; ++mt) {
        int rloc = rowbase + mt * 16 + quad * 4;
        #pragma unroll
        for (int nt = 0; nt < 8; ++nt) {
            int col = nt * 16 + l16;
            float bv = bl1[col];
            #pragma unroll
            for (int r = 0; r < 4; ++r) {
                float v = fmaxf(acc[mt][nt][r] + bv, 0.f);
                Al[(rloc + r) * LPAD + col] = (short)f2b(v);
            }
            acc[mt][nt] = (float4v){0.f, 0.f, 0.f, 0.f};
        }
    }
    // ---- layer 2 ----
    #pragma unroll
    for (int kc = 0; kc < 4; ++kc) {
        int koff = kc * 32 + quad * 8;
        short8 a0 = *(const short8*)&Al[(rowbase + l16) * LPAD + koff];
        short8 a1 = *(const short8*)&Al[(rowbase + 16 + l16) * LPAD + koff];
        #pragma unroll
        for (int nt = 0; nt < 8; ++nt) {
            short8 bfr = *(const short8*)&W2t[(nt * 16 + l16) * LPAD + koff];
            acc[0][nt] = __builtin_amdgcn_mfma_f32_16x16x32_bf16(a0, bfr, acc[0][nt], 0, 0, 0);
            acc[1][nt] = __builtin_amdgcn_mfma_f32_16x16x32_bf16(a1, bfr, acc[1][nt], 0, 0, 0);
        }
    }
    #pragma unroll
    for (int mt = 0; mt < 2; ++mt) {
        int rloc = rowbase + mt * 16 + quad * 4;
        #pragma unroll
        for (int nt = 0; nt < 8; ++nt) {
            int col = nt * 16 + l16;
            float bv = bl2[col];
            #pragma unroll
            for (int r = 0; r < 4; ++r) {
                int grow = row0 + rloc + r;
                if (grow < M)
                    out[(size_t)grow * 128 + col] = acc[mt][nt][r] + bv;
            }
        }
    }
}

extern "C" void kernel_launch(void* const* d_in, const int* in_sizes, int n_in,
                              void* d_out, int out_size, void* d_ws, size_t ws_size,
                              hipStream_t stream) {
    const float* x  = (const float*)d_in[0];
    const int*   ei = (const int*)d_in[1];
    const float* W1 = (const float*)d_in[2];
    const float* b1 = (const float*)d_in[3];
    const float* W2 = (const float*)d_in[4];
    const float* b2 = (const float*)d_in[5];
    float* out = (float*)d_out;

    // workspace layout (bytes):
    //   [0, 25,608,192)        cnt u16 matrix — dead after place
    //   [0, 12,800,000)        aggb slabs (bf16) — alias over cnt, written by gather
    //   [25,700,000, 32,100,000) rank — dead after place
    //   [32,100,000, 38,500,000) srcs
    //   [38,500,000, 51,300,000) xb slabs (bf16) — dead after gather
    //   [51,300,000 ...) deg, offsets, bsum, flag
    char* ws = (char*)d_ws;
    unsigned*       cntw    = (unsigned*)(ws);
    unsigned short* cnt16   = (unsigned short*)(ws);
    unsigned*       aggb2   = (unsigned*)(ws);
    int*            rank    = (int*)  (ws + 25700000);
    int*            srcs    = (int*)  (ws + 32100000);
    unsigned*       xb2     = (unsigned*)(ws + 38500000);
    int*            deg     = (int*)  (ws + 51300000);
    int*            offsets = (int*)  (ws + 51500000);
    int*            bsum    = (int*)  (ws + 51700000);
    int*            flag    = (int*)  (ws + 51710000);

    const int NB_SCAN = (N_NODES + 511) / 512;  // 98

    k_cvt<<<(N_NODES * 32 + 255) / 256, 256, 0, stream>>>(x, xb2, ei, flag);
    k_hist_rank<<<NB_H, 1024, 0, stream>>>(ei, flag, cntw, rank);
    k_colscan_scan1<<<NB_SCAN, 512, 0, stream>>>(cnt16, deg, offsets, bsum);
    k_scan23<<<NB_SCAN, 512, 0, stream>>>(offsets, bsum, NB_SCAN);
    k_place<<<(N_EDGES + 1023) / 1024, 1024, 0, stream>>>(ei, flag, offsets, cnt16, rank, srcs);
    for (int p = 0; p < NSLAB; ++p)
        k_gather<<<N_NODES / 4, 256, 0, stream>>>(xb2, srcs, offsets, deg, aggb2, p);

    int gblocks = (N_NODES + 127) / 128;  // 391
    k_mlp<<<gblocks, 256, 0, stream>>>(aggb2, W1, b1, W2, b2, out, N_NODES);
}

// Round 12
// 261.913 us; speedup vs baseline: 1.1824x; 1.1824x over previous
//
#include <hip/hip_runtime.h>
#include <hip/hip_bf16.h>

// GIN layer: out = relu(((1+eps)*x + segment_sum(x[src], dst)) @ W1 + b1) @ W2 + b2
// N=50000 nodes, E=1.6M edges, D=128.

#define N_NODES 50000
#define N_EDGES 1600000
#define D 128

#define NB_H 256                 // private histograms (one owner block each)
#define CHUNK (N_EDGES / NB_H)   // 6250 edges per chunk; rank max 6249 < 65536
#define HROW 50016               // ushorts per hist row (100,032 B, 128-aligned)

typedef __attribute__((ext_vector_type(8))) short short8;
typedef __attribute__((ext_vector_type(4))) float float4v;

__device__ inline unsigned short f2b(float f) {
    unsigned u = __builtin_bit_cast(unsigned, f);
    u = u + 0x7fffu + ((u >> 16) & 1u);  // RNE
    return (unsigned short)(u >> 16);
}
__device__ inline float b2f_lo(unsigned u) { return __builtin_bit_cast(float, u << 16); }
__device__ inline float b2f_hi(unsigned u) { return __builtin_bit_cast(float, u & 0xffff0000u); }

// ---------------- x f32 -> bf16 rows (+ edge-dtype detect, + zero sync counter) --------
__global__ __launch_bounds__(256) void k_cvt(const float* __restrict__ x,
                                             unsigned short* __restrict__ xb,
                                             const int* __restrict__ ei,
                                             int* __restrict__ flag,
                                             int* __restrict__ sync) {
    if (blockIdx.x == 0) {
        __shared__ int nz;
        if (threadIdx.x == 0) { nz = 0; *sync = 0; }
        __syncthreads();
        if (ei[threadIdx.x * 2 + 1] != 0) atomicAdd(&nz, 1);
        __syncthreads();
        if (threadIdx.x == 0) *flag = (nz == 0) ? 1 : 0;  // 1 => int64 layout
    }
    int i = blockIdx.x * blockDim.x + threadIdx.x;  // one float4 per thread
    if (i >= N_NODES * 32) return;
    float4 v = ((const float4*)x)[i];
    ushort4 o;
    o.x = f2b(v.x); o.y = f2b(v.y); o.z = f2b(v.z); o.w = f2b(v.w);
    ((ushort4*)xb)[i] = o;
}

// ---------------- LDS histogram (packed u16 pairs) + per-edge rank ----------------
__global__ __launch_bounds__(1024) void k_hist_rank(const int* __restrict__ ei,
                                                    const int* __restrict__ flag,
                                                    unsigned* __restrict__ cntw,
                                                    int* __restrict__ rank) {
    __shared__ unsigned hist[HROW / 2];  // 25008 u32 = 100,032 B
    int b = blockIdx.x;
    for (int i = threadIdx.x; i < HROW / 2; i += 1024) hist[i] = 0u;
    __syncthreads();
    int wide = *flag;
    int e0 = b * CHUNK;
    for (int i = threadIdx.x; i < CHUNK; i += 1024) {
        int e = e0 + i;
        long long di = (long long)N_EDGES + e;
        int d = wide ? ei[di * 2] : ei[di];
        int r = 0;
        if ((unsigned)d < (unsigned)N_NODES) {
            int sh = (d & 1) * 16;
            unsigned old = atomicAdd(&hist[d >> 1], 1u << sh);
            r = (old >> sh) & 0xffffu;
        }
        rank[e] = r;  // coalesced
    }
    __syncthreads();
    unsigned* row = cntw + (size_t)b * (HROW / 2);
    for (int i = threadIdx.x; i < HROW / 2; i += 1024) row[i] = hist[i];
}

// ---------------- fused CSR meta: colscan + local scan + global scan (spin) ------------
// 98 blocks launched alone on 256 CUs -> all co-resident; stream order serializes
// kernels, so the spin cannot deadlock.
__global__ __launch_bounds__(512) void k_csr(unsigned short* __restrict__ cnt16,
                                             int* __restrict__ deg,
                                             int* __restrict__ offsets,
                                             int* __restrict__ bsum,
                                             int* __restrict__ sync, int nb) {
    __shared__ int tmp[512];
    __shared__ int bs[128];
    int t = threadIdx.x;
    int d = blockIdx.x * 512 + t;
    int run = 0;
    if (d < N_NODES) {
        #pragma unroll 8
        for (int b = 0; b < NB_H; ++b) {
            size_t idx = (size_t)b * HROW + d;
            int v = cnt16[idx];
            cnt16[idx] = (unsigned short)run;
            run += v;
        }
        deg[d] = run;
    }
    tmp[t] = run;
    __syncthreads();
    for (int off = 1; off < 512; off <<= 1) {
        int u = (t >= off) ? tmp[t - off] : 0;
        __syncthreads();
        tmp[t] += u;
        __syncthreads();
    }
    int pe = tmp[t] - run;  // local exclusive prefix
    if (t == 511) {
        bsum[blockIdx.x] = tmp[511];
        __threadfence();
        __hip_atomic_fetch_add(sync, 1, __ATOMIC_RELEASE, __HIP_MEMORY_SCOPE_AGENT);
    }
    if (t == 0) {
        while (__hip_atomic_load(sync, __ATOMIC_ACQUIRE, __HIP_MEMORY_SCOPE_AGENT) < nb) { }
    }
    __syncthreads();
    if (t < 128) bs[t] = (t < nb) ? bsum[t] : 0;
    __syncthreads();
    for (int off = 1; off < 128; off <<= 1) {
        int v = (t >= off && t < 128) ? bs[t - off] : 0;
        __syncthreads();
        if (t < 128) bs[t] += v;
        __syncthreads();
    }
    int base = (blockIdx.x == 0) ? 0 : bs[blockIdx.x - 1];
    if (d < N_NODES) offsets[d] = pe + base;
}

// ---------------- CSR place (no atomics, one edge per thread, nt scatter store) --------
__global__ __launch_bounds__(1024) void k_place(const int* __restrict__ ei,
                                                const int* __restrict__ flag,
                                                const int* __restrict__ offsets,
                                                const unsigned short* __restrict__ cnt16,
                                                const int* __restrict__ rank,
                                                int* __restrict__ srcs) {
    int e = blockIdx.x * 1024 + threadIdx.x;
    if (e >= N_EDGES) return;
    int wide = *flag;
    int s = wide ? ei[(long long)e * 2] : ei[e];
    long long di = (long long)N_EDGES + e;
    int d = wide ? ei[di * 2] : ei[di];
    if ((unsigned)d < (unsigned)N_NODES && (unsigned)s < (unsigned)N_NODES) {
        int b = e / CHUNK;
        int pos = offsets[d] + cnt16[(size_t)b * HROW + d] + rank[e];
        __builtin_nontemporal_store(s, &srcs[pos]);  // scattered; nt avoids RFO
    }
}

// ---------------- gather: aggb[i] = bf16((1+eps)*x[i] + sum_{j in N(i)} x[j]) ----------
// One wave per node (block = 4 nodes). u=lane&15: row as 16 x uint4; g=lane>>4: 4 groups.
__global__ __launch_bounds__(256) void k_gather(const unsigned short* __restrict__ xb,
                                                const int* __restrict__ srcs,
                                                const int* __restrict__ offsets,
                                                const int* __restrict__ deg,
                                                unsigned short* __restrict__ aggb) {
    int node = blockIdx.x * 4 + (threadIdx.x >> 6);
    int lane = threadIdx.x & 63;
    int g = lane >> 4;    // neighbor group 0..3
    int u = lane & 15;    // uint4 index within row
    int beg = offsets[node];
    int end = beg + deg[node];
    const uint4* xr = (const uint4*)xb;
    float a0 = 0.f, a1 = 0.f, a2 = 0.f, a3 = 0.f, a4 = 0.f, a5 = 0.f, a6 = 0.f, a7 = 0.f;
    int j = beg + g;
    for (; j + 12 < end; j += 16) {
        int s0 = srcs[j];
        int s1 = srcs[j + 4];
        int s2 = srcs[j + 8];
        int s3 = srcs[j + 12];
        uint4 A = xr[(size_t)s0 * 16 + u];
        uint4 B = xr[(size_t)s1 * 16 + u];
        uint4 C = xr[(size_t)s2 * 16 + u];
        uint4 E = xr[(size_t)s3 * 16 + u];
        a0 += b2f_lo(A.x); a1 += b2f_hi(A.x); a2 += b2f_lo(A.y); a3 += b2f_hi(A.y);
        a4 += b2f_lo(A.z); a5 += b2f_hi(A.z); a6 += b2f_lo(A.w); a7 += b2f_hi(A.w);
        a0 += b2f_lo(B.x); a1 += b2f_hi(B.x); a2 += b2f_lo(B.y); a3 += b2f_hi(B.y);
        a4 += b2f_lo(B.z); a5 += b2f_hi(B.z); a6 += b2f_lo(B.w); a7 += b2f_hi(B.w);
        a0 += b2f_lo(C.x); a1 += b2f_hi(C.x); a2 += b2f_lo(C.y); a3 += b2f_hi(C.y);
        a4 += b2f_lo(C.z); a5 += b2f_hi(C.z); a6 += b2f_lo(C.w); a7 += b2f_hi(C.w);
        a0 += b2f_lo(E.x); a1 += b2f_hi(E.x); a2 += b2f_lo(E.y); a3 += b2f_hi(E.y);
        a4 += b2f_lo(E.z); a5 += b2f_hi(E.z); a6 += b2f_lo(E.w); a7 += b2f_hi(E.w);
    }
    for (; j < end; j += 4) {
        int s0 = srcs[j];
        uint4 A = xr[(size_t)s0 * 16 + u];
        a0 += b2f_lo(A.x); a1 += b2f_hi(A.x); a2 += b2f_lo(A.y); a3 += b2f_hi(A.y);
        a4 += b2f_lo(A.z); a5 += b2f_hi(A.z); a6 += b2f_lo(A.w); a7 += b2f_hi(A.w);
    }
    #pragma unroll
    for (int m = 16; m <= 32; m <<= 1) {
        a0 += __shfl_xor(a0, m, 64); a1 += __shfl_xor(a1, m, 64);
        a2 += __shfl_xor(a2, m, 64); a3 += __shfl_xor(a3, m, 64);
        a4 += __shfl_xor(a4, m, 64); a5 += __shfl_xor(a5, m, 64);
        a6 += __shfl_xor(a6, m, 64); a7 += __shfl_xor(a7, m, 64);
    }
    if (g == 0) {
        uint4 xs = xr[(size_t)node * 16 + u];  // self term (bf16)
        float f0 = fmaf(1.001f, b2f_lo(xs.x), a0), f1 = fmaf(1.001f, b2f_hi(xs.x), a1);
        float f2 = fmaf(1.001f, b2f_lo(xs.y), a2), f3 = fmaf(1.001f, b2f_hi(xs.y), a3);
        float f4 = fmaf(1.001f, b2f_lo(xs.z), a4), f5 = fmaf(1.001f, b2f_hi(xs.z), a5);
        float f6 = fmaf(1.001f, b2f_lo(xs.w), a6), f7 = fmaf(1.001f, b2f_hi(xs.w), a7);
        uint4 o;
        o.x = (unsigned)f2b(f0) | ((unsigned)f2b(f1) << 16);
        o.y = (unsigned)f2b(f2) | ((unsigned)f2b(f3) << 16);
        o.z = (unsigned)f2b(f4) | ((unsigned)f2b(f5) << 16);
        o.w = (unsigned)f2b(f6) | ((unsigned)f2b(f7) << 16);
        ((uint4*)aggb)[(size_t)node * 16 + u] = o;
    }
}

// ---------------- fused MLP: out = relu(A@W1+b1)@W2 + b2  (2 blocks/CU) ---------------
// W2^T is staged into W1^T's LDS buffer after layer 1 (barrier-protected), keeping
// LDS at ~70 KB so 2 blocks/CU fit. Each wave's K-loops read only its own 32 A-rows,
// so h overwrites those rows without an extra barrier.
#define LPAD 136
__global__ __launch_bounds__(256, 2) void k_mlp(const unsigned short* __restrict__ A,
                                                const float* __restrict__ W1g,
                                                const float* __restrict__ b1g,
                                                const float* __restrict__ W2g,
                                                const float* __restrict__ b2g,
                                                float* __restrict__ out, int M) {
    __shared__ short Al[128 * LPAD];    // [row][k] bf16
    __shared__ short Wt[128 * LPAD];    // [n][k] — W1^T then W2^T
    __shared__ float bl1[128], bl2[128];

    int t = threadIdx.x;
    int row0 = blockIdx.x * 128;

    // stage A (bf16 node-major, uint4 = 8 cols)
    const uint4* A16 = (const uint4*)A;
    #pragma unroll
    for (int i = 0; i < 8; ++i) {
        int idx = i * 256 + t;      // 0..2047
        int r = idx >> 4;           // 0..127
        int c = idx & 15;           // uint4 within row
        uint4 v = make_uint4(0u, 0u, 0u, 0u);
        if (row0 + r < M) v = A16[(size_t)(row0 + r) * 16 + c];
        *(uint4*)&Al[r * LPAD + c * 8] = v;
    }
    // stage W1^T
    const float4* W14 = (const float4*)W1g;
    #pragma unroll
    for (int i = 0; i < 16; ++i) {
        int idx = i * 256 + t;
        int k = idx >> 5;
        int n4 = idx & 31;
        float4 v1 = W14[k * 32 + n4];
        Wt[(n4 * 4 + 0) * LPAD + k] = (short)f2b(v1.x);
        Wt[(n4 * 4 + 1) * LPAD + k] = (short)f2b(v1.y);
        Wt[(n4 * 4 + 2) * LPAD + k] = (short)f2b(v1.z);
        Wt[(n4 * 4 + 3) * LPAD + k] = (short)f2b(v1.w);
    }
    if (t < 32) ((float4*)bl1)[t] = ((const float4*)b1g)[t];
    else if (t < 64) ((float4*)bl2)[t - 32] = ((const float4*)b2g)[t - 32];
    __syncthreads();

    int wave = t >> 6;
    int lane = t & 63;
    int quad = lane >> 4;
    int l16 = lane & 15;
    int rowbase = wave * 32;

    float4v acc[2][8];
    #pragma unroll
    for (int mt = 0; mt < 2; ++mt)
        #pragma unroll
        for (int nt = 0; nt < 8; ++nt)
            acc[mt][nt] = (float4v){0.f, 0.f, 0.f, 0.f};

    // ---- layer 1 ----
    #pragma unroll
    for (int kc = 0; kc < 4; ++kc) {
        int koff = kc * 32 + quad * 8;
        short8 a0 = *(const short8*)&Al[(rowbase + l16) * LPAD + koff];
        short8 a1 = *(const short8*)&Al[(rowbase + 16 + l16) * LPAD + koff];
        #pragma unroll
        for (int nt = 0; nt < 8; ++nt) {
            short8 bfr = *(const short8*)&Wt[(nt * 16 + l16) * LPAD + koff];
            acc[0][nt] = __builtin_amdgcn_mfma_f32_16x16x32_bf16(a0, bfr, acc[0][nt], 0, 0, 0);
            acc[1][nt] = __builtin_amdgcn_mfma_f32_16x16x32_bf16(a1, bfr, acc[1][nt], 0, 0, 0);
        }
    }
    // h = relu(acc + b1) -> this wave's own Al rows (bf16)
    #pragma unroll
    for (int mt = 0; mt < 2; ++mt) {
        int rloc = rowbase + mt * 16 + quad * 4;
        #pragma unroll
        for (int nt = 0; nt < 8; ++nt) {
            int col = nt * 16 + l16;
            float bv = bl1[col];
            #pragma unroll
            for (int r = 0; r < 4; ++r) {
                float v = fmaxf(acc[mt][nt][r] + bv, 0.f);
                Al[(rloc + r) * LPAD + col] = (short)f2b(v);
            }
            acc[mt][nt] = (float4v){0.f, 0.f, 0.f, 0.f};
        }
    }
    __syncthreads();  // all waves done reading W1^T and writing h
    // stage W2^T over W1^T
    const float4* W24 = (const float4*)W2g;
    #pragma unroll
    for (int i = 0; i < 16; ++i) {
        int idx = i * 256 + t;
        int k = idx >> 5;
        int n4 = idx & 31;
        float4 v2 = W24[k * 32 + n4];
        Wt[(n4 * 4 + 0) * LPAD + k] = (short)f2b(v2.x);
        Wt[(n4 * 4 + 1) * LPAD + k] = (short)f2b(v2.y);
        Wt[(n4 * 4 + 2) * LPAD + k] = (short)f2b(v2.z);
        Wt[(n4 * 4 + 3) * LPAD + k] = (short)f2b(v2.w);
    }
    __syncthreads();
    // ---- layer 2 ----
    #pragma unroll
    for (int kc = 0; kc < 4; ++kc) {
        int koff = kc * 32 + quad * 8;
        short8 a0 = *(const short8*)&Al[(rowbase + l16) * LPAD + koff];
        short8 a1 = *(const short8*)&Al[(rowbase + 16 + l16) * LPAD + koff];
        #pragma unroll
        for (int nt = 0; nt < 8; ++nt) {
            short8 bfr = *(const short8*)&Wt[(nt * 16 + l16) * LPAD + koff];
            acc[0][nt] = __builtin_amdgcn_mfma_f32_16x16x32_bf16(a0, bfr, acc[0][nt], 0, 0, 0);
            acc[1][nt] = __builtin_amdgcn_mfma_f32_16x16x32_bf16(a1, bfr, acc[1][nt], 0, 0, 0);
        }
    }
    #pragma unroll
    for (int mt = 0; mt < 2; ++mt) {
        int rloc = rowbase + mt * 16 + quad * 4;
        #pragma unroll
        for (int nt = 0; nt < 8; ++nt) {
            int col = nt * 16 + l16;
            float bv = bl2[col];
            #pragma unroll
            for (int r = 0; r < 4; ++r) {
                int grow = row0 + rloc + r;
                if (grow < M)
                    out[(size_t)grow * 128 + col] = acc[mt][nt][r] + bv;
            }
        }
    }
}

extern "C" void kernel_launch(void* const* d_in, const int* in_sizes, int n_in,
                              void* d_out, int out_size, void* d_ws, size_t ws_size,
                              hipStream_t stream) {
    const float* x  = (const float*)d_in[0];
    const int*   ei = (const int*)d_in[1];
    const float* W1 = (const float*)d_in[2];
    const float* b1 = (const float*)d_in[3];
    const float* W2 = (const float*)d_in[4];
    const float* b2 = (const float*)d_in[5];
    float* out = (float*)d_out;

    // workspace layout (bytes):
    //   [0, 25,608,192)          cnt u16 matrix — dead after place
    //   [0, 12,800,000)          aggb (bf16 node-major) — alias over cnt, by gather
    //   [25,700,000, 32,100,000) rank — dead after place
    //   [32,100,000, 38,500,000) srcs
    //   [38,500,000, 51,300,000) xb (bf16 node-major) — dead after gather
    //   [51,300,000 ...)         deg, offsets, bsum, flag, sync
    char* ws = (char*)d_ws;
    unsigned*       cntw    = (unsigned*)(ws);
    unsigned short* cnt16   = (unsigned short*)(ws);
    unsigned short* aggb    = (unsigned short*)(ws);
    int*            rank    = (int*)  (ws + 25700000);
    int*            srcs    = (int*)  (ws + 32100000);
    unsigned short* xb      = (unsigned short*)(ws + 38500000);
    int*            deg     = (int*)  (ws + 51300000);
    int*            offsets = (int*)  (ws + 51500000);
    int*            bsum    = (int*)  (ws + 51700000);
    int*            flag    = (int*)  (ws + 51710000);
    int*            sync    = (int*)  (ws + 51710064);

    const int NB_SCAN = (N_NODES + 511) / 512;  // 98

    k_cvt<<<(N_NODES * 32 + 255) / 256, 256, 0, stream>>>(x, xb, ei, flag, sync);
    k_hist_rank<<<NB_H, 1024, 0, stream>>>(ei, flag, cntw, rank);
    k_csr<<<NB_SCAN, 512, 0, stream>>>(cnt16, deg, offsets, bsum, sync, NB_SCAN);
    k_place<<<(N_EDGES + 1023) / 1024, 1024, 0, stream>>>(ei, flag, offsets, cnt16, rank, srcs);
    k_gather<<<N_NODES / 4, 256, 0, stream>>>(xb, srcs, offsets, deg, aggb);
    k_mlp<<<(N_NODES + 127) / 128, 256, 0, stream>>>(aggb, W1, b1, W2, b2, out, N_NODES);
}